// Round 11
// baseline (250.909 us; speedup 1.0000x reference)
//
#include <hip/hip_runtime.h>

#define N_NODES 100000
#define N_EDGES 1250000
#define D 64

#define BIN_SHIFT 8
#define BIN_NODES 256
#define NBINS ((N_NODES + BIN_NODES - 1) >> BIN_SHIFT)   // 391
#define BIN_CAP 4096     // mean 3197/bin, sigma ~56 -> +16 sigma safe
#define SLAB (BIN_CAP + 3 * BIN_NODES)   // 4864: worst-case x4 padding
#define CHUNK 2048       // edges per bin_kernel block
#define ZERO_NODE N_NODES   // virtual all-zero row for padding

typedef __attribute__((ext_vector_type(8))) short short8;   // 8 bf16 (4 VGPRs)
typedef __attribute__((ext_vector_type(4))) float f32x4;    // MFMA acc

// ---- bf16 helpers (finite values only) ----
__device__ inline unsigned short f2bf(float f) {
    unsigned int u = __float_as_uint(f);
    unsigned int r = (u + 0x7fffu + ((u >> 16) & 1u)) >> 16;
    return (unsigned short)r;
}
__device__ inline float4 unpack_bf4(uint2 u) {
    float4 f;
    f.x = __uint_as_float(u.x << 16);
    f.y = __uint_as_float(u.x & 0xffff0000u);
    f.z = __uint_as_float(u.y << 16);
    f.w = __uint_as_float(u.y & 0xffff0000u);
    return f;
}

// ------- x fp32 -> bf16 + zero bin counters + zero virtual rows + build wt -------
__global__ __launch_bounds__(256)
void convert_zero_kernel(const float4* __restrict__ xin, ushort4* __restrict__ xb,
                         int n4, int* __restrict__ bin_cnt,
                         unsigned int* __restrict__ xb_zrow,
                         unsigned int* __restrict__ h_zrow,
                         const float* __restrict__ Wl1, const float* __restrict__ Wr1,
                         const float* __restrict__ Wl2, const float* __restrict__ Wr2,
                         unsigned short* __restrict__ wt) {
    int i = blockIdx.x * 256 + threadIdx.x;
    if (i < n4) {
        float4 v = xin[i];
        ushort4 u;
        u.x = f2bf(v.x); u.y = f2bf(v.y); u.z = f2bf(v.z); u.w = f2bf(v.w);
        xb[i] = u;
    }
    if (i < NBINS) bin_cnt[i] = 0;
    if (i < 32) { xb_zrow[i] = 0u; h_zrow[i] = 0u; }
    if (i < 2 * 64 * 128) {
        int layer = i >> 13;
        int n = (i >> 7) & 63;
        int k = i & 127;
        const float* W = layer ? (k < 64 ? Wl2 : Wr2) : (k < 64 ? Wl1 : Wr1);
        float v = W[(k & 63) * D + n];
        wt[i] = f2bf(v);
    }
}

// ---------------- pass 1: LDS-aggregated binning by dst>>8 ----------------
// thread t owns bins 2t, 2t+1 in the scan (NBINS=391 <= 512).
__global__ __launch_bounds__(256)
void bin_kernel(const int* __restrict__ src, const int* __restrict__ dst,
                int* __restrict__ bin_cnt, int* __restrict__ slabs) {
    __shared__ int lhist[NBINS];
    __shared__ int lstart[NBINS];
    __shared__ int lbase[NBINS];
    __shared__ int lcur[NBINS];
    __shared__ int pscan[256];
    __shared__ int sval[CHUNK];
    __shared__ int sdst[CHUNK];

    const int t = threadIdx.x;
    const int e0 = blockIdx.x * CHUNK;
    int cnt = N_EDGES - e0; if (cnt > CHUNK) cnt = CHUNK;

    for (int i = t; i < NBINS; i += 256) lhist[i] = 0;
    __syncthreads();

    for (int i = t; i < cnt; i += 256)
        atomicAdd(&lhist[dst[e0 + i] >> BIN_SHIFT], 1);
    __syncthreads();

    int h0 = (2 * t < NBINS) ? lhist[2 * t] : 0;
    int h1 = (2 * t + 1 < NBINS) ? lhist[2 * t + 1] : 0;
    int pv = h0 + h1;
    pscan[t] = pv;
    __syncthreads();
    for (int off = 1; off < 256; off <<= 1) {
        int x = (t >= off) ? pscan[t - off] : 0;
        __syncthreads();
        pscan[t] += x;
        __syncthreads();
    }
    int excl = pscan[t] - pv;
    if (2 * t < NBINS) {
        lstart[2 * t] = excl; lcur[2 * t] = excl;
        lbase[2 * t] = (h0 > 0) ? atomicAdd(&bin_cnt[2 * t], h0) : 0;
    }
    if (2 * t + 1 < NBINS) {
        lstart[2 * t + 1] = excl + h0; lcur[2 * t + 1] = excl + h0;
        lbase[2 * t + 1] = (h1 > 0) ? atomicAdd(&bin_cnt[2 * t + 1], h1) : 0;
    }
    __syncthreads();

    for (int i = t; i < cnt; i += 256) {
        int d = dst[e0 + i];
        int s = src[e0 + i];
        int b = d >> BIN_SHIFT;
        int slot = atomicAdd(&lcur[b], 1);
        int rank = slot - lstart[b];
        sval[slot] = (s << BIN_SHIFT) | (d & (BIN_NODES - 1));
        int gp = lbase[b] + rank;
        sdst[slot] = (gp < BIN_CAP) ? (b * SLAB + gp) : -1;
    }
    __syncthreads();

    for (int i = t; i < cnt; i += 256) {
        int dd = sdst[i];
        if (dd >= 0) slabs[dd] = sval[i];
    }
}

// ---------------- pass 2: per-bin LDS counting sort -> padded CSR (in place) ----
// Block = bin of 256 nodes; thread t owns node t. ~19 KB LDS, 391 blocks.
__global__ __launch_bounds__(256)
void bin_sort_kernel(int* __restrict__ slabs, const int* __restrict__ bin_cnt,
                     int* __restrict__ deg_out, int* __restrict__ rstart_out) {
    __shared__ int hist[BIN_NODES];
    __shared__ int cur[BIN_NODES];
    __shared__ int stage[BIN_CAP];

    const int b = blockIdx.x;
    const int t = threadIdx.x;
    int cnt = bin_cnt[b]; if (cnt > BIN_CAP) cnt = BIN_CAP;
    const int nb0 = b << BIN_SHIFT;
    const int nn = (N_NODES - nb0 < BIN_NODES) ? (N_NODES - nb0) : BIN_NODES;
    const int slab0 = b * SLAB;

    hist[t] = 0;
    __syncthreads();

    for (int i = t; i < cnt; i += 256) {
        int p = slabs[slab0 + i];
        stage[i] = p;
        atomicAdd(&hist[p & (BIN_NODES - 1)], 1);
    }
    __syncthreads();

    int h = hist[t];
    int ph = (h + 3) & ~3;
    int pv = ph;
    cur[t] = pv;   // reuse as scan scratch
    __syncthreads();
    for (int off = 1; off < 256; off <<= 1) {
        int x = (t >= off) ? cur[t - off] : 0;
        __syncthreads();
        cur[t] += x;
        __syncthreads();
    }
    int excl = cur[t] - pv;
    __syncthreads();
    cur[t] = excl;
    if (t < nn) {
        deg_out[nb0 + t] = h;
        rstart_out[nb0 + t] = slab0 + excl;
        for (int i = h; i < ph; ++i) slabs[slab0 + excl + i] = ZERO_NODE;
    }
    __syncthreads();

    for (int i = t; i < cnt; i += 256) {
        int p = stage[i];
        int pos = atomicAdd(&cur[p & (BIN_NODES - 1)], 1);
        slabs[slab0 + pos] = p >> BIN_SHIFT;
    }
}

// ---- one 64-edge batch of the quad gather ----
__device__ inline void gather_batch(const uint2* __restrict__ xin64, int idx,
                                    int m, int q, int f2, float4& a) {
    int quads = m >> 2;
    float4 c0 = make_float4(0.f, 0.f, 0.f, 0.f);
    float4 c1 = make_float4(0.f, 0.f, 0.f, 0.f);
    float4 c2 = make_float4(0.f, 0.f, 0.f, 0.f);
    float4 c3 = make_float4(0.f, 0.f, 0.f, 0.f);
    int t = 0;
    for (; t + 4 <= quads; t += 4) {
        int sA = __shfl(idx, 4 * t + q);
        int sB = __shfl(idx, 4 * t + 4 + q);
        int sC = __shfl(idx, 4 * t + 8 + q);
        int sD = __shfl(idx, 4 * t + 12 + q);
        float4 fA = unpack_bf4(xin64[(size_t)sA * 16 + f2]);
        float4 fB = unpack_bf4(xin64[(size_t)sB * 16 + f2]);
        float4 fC = unpack_bf4(xin64[(size_t)sC * 16 + f2]);
        float4 fD = unpack_bf4(xin64[(size_t)sD * 16 + f2]);
        c0.x += fA.x; c0.y += fA.y; c0.z += fA.z; c0.w += fA.w;
        c1.x += fB.x; c1.y += fB.y; c1.z += fB.z; c1.w += fB.w;
        c2.x += fC.x; c2.y += fC.y; c2.z += fC.z; c2.w += fC.w;
        c3.x += fD.x; c3.y += fD.y; c3.z += fD.z; c3.w += fD.w;
    }
    for (; t + 2 <= quads; t += 2) {
        int sA = __shfl(idx, 4 * t + q);
        int sB = __shfl(idx, 4 * t + 4 + q);
        float4 fA = unpack_bf4(xin64[(size_t)sA * 16 + f2]);
        float4 fB = unpack_bf4(xin64[(size_t)sB * 16 + f2]);
        c0.x += fA.x; c0.y += fA.y; c0.z += fA.z; c0.w += fA.w;
        c1.x += fB.x; c1.y += fB.y; c1.z += fB.z; c1.w += fB.w;
    }
    for (; t < quads; ++t) {
        int sA = __shfl(idx, 4 * t + q);
        float4 fA = unpack_bf4(xin64[(size_t)sA * 16 + f2]);
        c0.x += fA.x; c0.y += fA.y; c0.z += fA.z; c0.w += fA.w;
    }
    a.x += (c0.x + c1.x) + (c2.x + c3.x);
    a.y += (c0.y + c1.y) + (c2.y + c3.y);
    a.z += (c0.z + c1.z) + (c2.z + c3.z);
    a.w += (c0.w + c1.w) + (c2.w + c3.w);
}

// ---------------- fused layer: gather-mean + MFMA GEMM ----------------
// Two independent row-chains per wave (rows r, r+4) to raise MLP at the
// idx->shfl->rowload chain start. GEMM: mfma_f32_16x16x32_bf16, K=128.
template <typename TOUT>
__global__ __launch_bounds__(256, 8)
void fused_layer_kernel(const unsigned short* __restrict__ xin,   // bf16 [N+1,D]
                        const int* __restrict__ rstart,
                        const int* __restrict__ deg,
                        const int* __restrict__ sorted_src,
                        const unsigned short* __restrict__ wt,    // bf16 [64][128]
                        const float* __restrict__ bl,
                        TOUT* __restrict__ out,
                        int relu) {
    __shared__ __align__(16) unsigned short sA[32][136];   // [row][k: mean|x]

    const uint2* __restrict__ xin64 = (const uint2*)xin;

    const int tid = threadIdx.x;
    const int row0 = blockIdx.x * 32;

    const int wave = tid >> 6;
    const int lane = tid & 63;
    const int q  = lane >> 4;
    const int f2 = lane & 15;

    for (int r = wave; r < 32; r += 8) {
        int n1 = row0 + r;
        int n2 = row0 + r + 4;
        int dg1 = deg[n1], dg2 = deg[n2];
        int pdg1 = (dg1 + 3) & ~3, pdg2 = (dg2 + 3) & ~3;
        int st1 = rstart[n1], st2 = rstart[n2];
        uint2 xraw1 = xin64[(size_t)n1 * 16 + f2];
        uint2 xraw2 = xin64[(size_t)n2 * 16 + f2];
        float4 a1 = make_float4(0.f, 0.f, 0.f, 0.f);
        float4 a2 = make_float4(0.f, 0.f, 0.f, 0.f);

        for (int base = 0; base < pdg1 || base < pdg2; base += 64) {
            int m1 = pdg1 - base; if (m1 > 64) m1 = 64;
            int m2 = pdg2 - base; if (m2 > 64) m2 = 64;
            int idx1 = 0, idx2 = 0;
            if (lane < m1) idx1 = sorted_src[st1 + base + lane];
            if (lane < m2) idx2 = sorted_src[st2 + base + lane];
            if (m1 > 0) gather_batch(xin64, idx1, m1, q, f2, a1);
            if (m2 > 0) gather_batch(xin64, idx2, m2, q, f2, a2);
        }

        a1.x += __shfl_xor(a1.x, 16); a1.y += __shfl_xor(a1.y, 16);
        a1.z += __shfl_xor(a1.z, 16); a1.w += __shfl_xor(a1.w, 16);
        a1.x += __shfl_xor(a1.x, 32); a1.y += __shfl_xor(a1.y, 32);
        a1.z += __shfl_xor(a1.z, 32); a1.w += __shfl_xor(a1.w, 32);
        a2.x += __shfl_xor(a2.x, 16); a2.y += __shfl_xor(a2.y, 16);
        a2.z += __shfl_xor(a2.z, 16); a2.w += __shfl_xor(a2.w, 16);
        a2.x += __shfl_xor(a2.x, 32); a2.y += __shfl_xor(a2.y, 32);
        a2.z += __shfl_xor(a2.z, 32); a2.w += __shfl_xor(a2.w, 32);

        if (q == 0) {
            float inv1 = 1.0f / (float)(dg1 > 0 ? dg1 : 1);
            float inv2 = 1.0f / (float)(dg2 > 0 ? dg2 : 1);
            unsigned int p0 = (unsigned int)f2bf(a1.x * inv1) |
                              ((unsigned int)f2bf(a1.y * inv1) << 16);
            unsigned int p1 = (unsigned int)f2bf(a1.z * inv1) |
                              ((unsigned int)f2bf(a1.w * inv1) << 16);
            *(uint2*)&sA[r][f2 * 4] = make_uint2(p0, p1);
            *(uint2*)&sA[r][64 + f2 * 4] = xraw1;
            p0 = (unsigned int)f2bf(a2.x * inv2) |
                 ((unsigned int)f2bf(a2.y * inv2) << 16);
            p1 = (unsigned int)f2bf(a2.z * inv2) |
                 ((unsigned int)f2bf(a2.w * inv2) << 16);
            *(uint2*)&sA[r + 4][f2 * 4] = make_uint2(p0, p1);
            *(uint2*)&sA[r + 4][64 + f2 * 4] = xraw2;
        }
    }
    __syncthreads();

    // ---- MFMA GEMM phase ----
    const int tm = wave & 1;
    const int tn0 = (wave >> 1) * 2;
    const int mrow = tm * 16 + (lane & 15);
    const int kq = (lane >> 4) * 8;

    short8 afr[4];
#pragma unroll
    for (int kk = 0; kk < 4; ++kk)
        afr[kk] = *(const short8*)&sA[mrow][kk * 32 + kq];

#pragma unroll
    for (int ti = 0; ti < 2; ++ti) {
        const int tn = tn0 + ti;
        const int col = tn * 16 + (lane & 15);
        float bias = bl[col];
        f32x4 acc = {bias, bias, bias, bias};
#pragma unroll
        for (int kk = 0; kk < 4; ++kk) {
            short8 bfr = *(const short8*)&wt[col * 128 + kk * 32 + kq];
            acc = __builtin_amdgcn_mfma_f32_16x16x32_bf16(afr[kk], bfr, acc, 0, 0, 0);
        }
        const int r0 = row0 + tm * 16 + (lane >> 4) * 4;
#pragma unroll
        for (int reg = 0; reg < 4; ++reg) {
            float o = relu ? fmaxf(acc[reg], 0.f) : acc[reg];
            if constexpr (__hip_internal::is_same<TOUT, unsigned short>::value)
                out[(size_t)(r0 + reg) * D + col] = f2bf(o);
            else
                out[(size_t)(r0 + reg) * D + col] = o;
        }
    }
}

extern "C" void kernel_launch(void* const* d_in, const int* in_sizes, int n_in,
                              void* d_out, int out_size, void* d_ws, size_t ws_size,
                              hipStream_t stream) {
    const float* x   = (const float*)d_in[0];
    const int*   ei  = (const int*)d_in[1];
    const float* Wl1 = (const float*)d_in[2];
    const float* b1  = (const float*)d_in[3];
    const float* Wr1 = (const float*)d_in[4];
    const float* Wl2 = (const float*)d_in[5];
    const float* b2  = (const float*)d_in[6];
    const float* Wr2 = (const float*)d_in[7];

    const int* src = ei;
    const int* dst = ei + N_EDGES;

    // ws (ints): slabs[391*4864] | bin_cnt[512] | deg[N] | rstart[N] |
    //            wt[2][64][128] bf16 | h_bf16[(N+1)*D]   (~21.3 MB)
    int* slabs   = (int*)d_ws;
    int* bin_cnt = slabs + (size_t)NBINS * SLAB;
    int* deg     = bin_cnt + 512;
    int* rstart  = deg + N_NODES;
    unsigned short* wt_all = (unsigned short*)(rstart + N_NODES);
    unsigned short* wt1 = wt_all;
    unsigned short* wt2 = wt_all + 64 * 128;
    unsigned short* h = wt_all + 2 * 64 * 128;   // [N+1, D] bf16
    float* out = (float*)d_out;
    unsigned short* xb = (unsigned short*)d_out;  // bf16 x scratch in d_out

    const int dense_blocks = N_NODES / 32;   // 3125
    const int conv4 = N_NODES * D / 4;
    const int bin_blocks = (N_EDGES + CHUNK - 1) / CHUNK;   // 611

    convert_zero_kernel<<<(conv4 + 255) / 256, 256, 0, stream>>>(
        (const float4*)x, (ushort4*)xb, conv4, bin_cnt,
        (unsigned int*)(xb + (size_t)ZERO_NODE * D),
        (unsigned int*)(h + (size_t)ZERO_NODE * D),
        Wl1, Wr1, Wl2, Wr2, wt_all);

    bin_kernel<<<bin_blocks, 256, 0, stream>>>(src, dst, bin_cnt, slabs);
    bin_sort_kernel<<<NBINS, 256, 0, stream>>>(slabs, bin_cnt, deg, rstart);

    fused_layer_kernel<unsigned short><<<dense_blocks, 256, 0, stream>>>(
        xb, rstart, deg, slabs, wt1, b1, h, /*relu=*/1);
    fused_layer_kernel<float><<<dense_blocks, 256, 0, stream>>>(
        h, rstart, deg, slabs, wt2, b2, out, /*relu=*/0);
}